// Round 1
// baseline (291.567 us; speedup 1.0000x reference)
//
#include <hip/hip_runtime.h>
#include <math.h>

#define HW 48
#define NPIX 2304          // 48*48
#define CF 64
#define CQ 32
#define RAD 12
#define PP 25
#define NTAP 625           // 25*25
#define KTOP 20
#define DILINT 16
#define QW 192

// ---- helpers ---------------------------------------------------------------

// ref_index may arrive as int32 or int64; detect via first 8 bytes.
__device__ inline int read_ref_index(const void* rip, int r) {
    const long long* p64 = (const long long*)rip;
    long long v0 = p64[0];
    if (v0 >= 0 && v0 < 1000000) return (int)p64[r];   // plausible int64 layout
    return ((const int*)rip)[r];                       // int32 layout
}

__device__ inline float dot64(const float* __restrict__ a_sh,
                              const float* __restrict__ b_glob) {
    const float4* a4 = (const float4*)a_sh;
    const float4* b4 = (const float4*)b_glob;
    float s = 0.f;
#pragma unroll
    for (int i = 0; i < 16; ++i) {
        float4 aa = a4[i];
        float4 bb = b4[i];
        s += aa.x * bb.x + aa.y * bb.y + aa.z * bb.z + aa.w * bb.w;
    }
    return s;
}

__device__ inline float blockReduceMax(float v, float* red, int tid) {
    red[tid] = v; __syncthreads();
    for (int s = 128; s > 0; s >>= 1) {
        if (tid < s) red[tid] = fmaxf(red[tid], red[tid + s]);
        __syncthreads();
    }
    float r0 = red[0]; __syncthreads();
    return r0;
}

__device__ inline float blockReduceSum(float v, float* red, int tid) {
    red[tid] = v; __syncthreads();
    for (int s = 128; s > 0; s >>= 1) {
        if (tid < s) red[tid] += red[tid + s];
        __syncthreads();
    }
    float r0 = red[0]; __syncthreads();
    return r0;
}

// ---- kernel 1: layout prep -------------------------------------------------
// ftT[p][c]  <- feats_t[c][p]
// frT[r][p][c] <- feats_r[r][c][p]
// qrT[r][p][c] <- quantized_r[r][c][4y][4x]   (the ::4,::4 downsample)
__global__ void prep_kernel(const float* __restrict__ fr,
                            const float* __restrict__ ft,
                            const float* __restrict__ q, int nref,
                            float* __restrict__ ftT,
                            float* __restrict__ frT,
                            float* __restrict__ qrT) {
    int i = blockIdx.x * blockDim.x + threadIdx.x;
    int tft = NPIX * CF;
    int tfr = nref * NPIX * CF;
    int tqr = nref * NPIX * CQ;
    if (i < tft) {
        int p = i >> 6, c = i & 63;
        ftT[i] = ft[c * NPIX + p];
    } else if (i < tft + tfr) {
        int j = i - tft;
        int rr = j / (NPIX * CF);
        int rem = j % (NPIX * CF);
        int p = rem >> 6, c = rem & 63;
        frT[j] = fr[((size_t)rr * CF + c) * NPIX + p];
    } else if (i < tft + tfr + tqr) {
        int j = i - tft - tfr;
        int rr = j / (NPIX * CQ);
        int rem = j % (NPIX * CQ);
        int p = rem >> 5, c = rem & 31;
        int y = p / HW, x = p % HW;
        qrT[j] = q[(((size_t)rr * CQ + c) * QW + 4 * y) * QW + 4 * x];
    }
}

// ---- kernel 2: correlation + (long: softmax offsets + bilinear corr) + topK
__global__ __launch_bounds__(256) void corr_topk_kernel(
    const float* __restrict__ ftT, const float* __restrict__ frT,
    const void* __restrict__ refIdx, const void* __restrict__ curInd,
    float* __restrict__ offY, float* __restrict__ offX,
    float* __restrict__ vals, int* __restrict__ topi) {
    __shared__ __align__(16) float ftv[CF];
    __shared__ float corr[NTAP];
    __shared__ float dgrid[26 * 26];
    __shared__ float red[256];
    __shared__ int redi[256];

    int p = blockIdx.x, r = blockIdx.y;
    int y = p / HW, x = p % HW;
    int tid = threadIdx.x;

    int cur = ((const int*)curInd)[0];
    int gap = cur - read_ref_index(refIdx, r);
    bool isLong = gap > DILINT;
    int dil = isLong ? min(4, gap / DILINT + 1) : 1;

    if (tid < CF) ftv[tid] = ftT[(size_t)p * CF + tid];
    __syncthreads();

    // integer-tap local correlation (dil = dirate for long, 1 for short)
    for (int t = tid; t < NTAP; t += 256) {
        int dy = t / PP - RAD, dx = t % PP - RAD;
        int yy = y + dy * dil, xx = x + dx * dil;
        float v = 0.f;
        if (yy >= 0 && yy < HW && xx >= 0 && xx < HW)
            v = dot64(ftv, &frT[((size_t)r * NPIX + yy * HW + xx) * CF]);
        corr[t] = v;
    }
    __syncthreads();

    if (isLong) {
        // softmax over 625 taps -> expected offsets
        float lm = -INFINITY;
        for (int t = tid; t < NTAP; t += 256) lm = fmaxf(lm, corr[t]);
        float M = blockReduceMax(lm, red, tid);
        float s0 = 0.f, sy = 0.f, sx = 0.f;
        for (int t = tid; t < NTAP; t += 256) {
            float e = expf(corr[t] - M);
            s0 += e;
            sy += e * (float)(t / PP - RAD);
            sx += e * (float)(t % PP - RAD);
        }
        s0 = blockReduceSum(s0, red, tid);
        sy = blockReduceSum(sy, red, tid);
        sx = blockReduceSum(sx, red, tid);
        float oy = sy / s0 * (float)dil;
        float ox = sx / s0 * (float)dil;
        if (tid == 0) { offY[r * NPIX + p] = oy; offX[r * NPIX + p] = ox; }

        // second correlation: bilinear taps at (y+oy+dy, x+ox+dx), dy,dx in [-12,12].
        // fractional part is constant per pixel -> 26x26 corner-dot grid + blend.
        float fy = (float)y + oy, fx = (float)x + ox;
        float fy0 = floorf(fy), fx0 = floorf(fx);
        float wy = fy - fy0, wx = fx - fx0;
        int iy0 = (int)fy0, ix0 = (int)fx0;
        for (int t = tid; t < 26 * 26; t += 256) {
            int a = t / 26, bcol = t % 26;
            int yy = iy0 - RAD + a, xx = ix0 - RAD + bcol;
            float v = 0.f;
            if (yy >= 0 && yy < HW && xx >= 0 && xx < HW)
                v = dot64(ftv, &frT[((size_t)r * NPIX + yy * HW + xx) * CF]);
            dgrid[t] = v;
        }
        __syncthreads();
        float w00 = (1.f - wy) * (1.f - wx), w01 = (1.f - wy) * wx;
        float w10 = wy * (1.f - wx), w11 = wy * wx;
        for (int t = tid; t < NTAP; t += 256) {
            int a = t / PP, bcol = t % PP;
            corr[t] = w00 * dgrid[a * 26 + bcol] + w01 * dgrid[a * 26 + bcol + 1] +
                      w10 * dgrid[(a + 1) * 26 + bcol] + w11 * dgrid[(a + 1) * 26 + bcol + 1];
        }
        __syncthreads();
    }

    // top-K selection, ties -> lowest index (lax.top_k semantics)
    for (int k = 0; k < KTOP; ++k) {
        float bv = -INFINITY; int bi = NTAP;
        for (int t = tid; t < NTAP; t += 256) {
            float v = corr[t];
            if (v > bv) { bv = v; bi = t; }   // strided ascending scan keeps lowest idx on tie
        }
        red[tid] = bv; redi[tid] = bi; __syncthreads();
        for (int s = 128; s > 0; s >>= 1) {
            if (tid < s) {
                float ov = red[tid + s]; int oi = redi[tid + s];
                if (ov > red[tid] || (ov == red[tid] && oi < redi[tid])) {
                    red[tid] = ov; redi[tid] = oi;
                }
            }
            __syncthreads();
        }
        if (tid == 0) {
            vals[((size_t)r * KTOP + k) * NPIX + p] = red[0];
            topi[((size_t)r * KTOP + k) * NPIX + p] = redi[0];
            corr[redi[0]] = -INFINITY;
        }
        __syncthreads();
    }
}

// ---- kernel 3: softmax over 60 vals + gather colors + blend ---------------
__global__ __launch_bounds__(256) void finalize_kernel(
    const float* __restrict__ qrT, const float* __restrict__ vals,
    const int* __restrict__ topi, const float* __restrict__ offY,
    const float* __restrict__ offX, const void* __restrict__ refIdx,
    const void* __restrict__ curInd, int nref, float* __restrict__ out) {
    int tid = threadIdx.x;
    int p = blockIdx.x * 8 + (tid >> 5);
    int c = tid & 31;
    if (p >= NPIX) return;
    int y = p / HW, x = p % HW;
    int cur = ((const int*)curInd)[0];
    int nk = nref * KTOP;

    float m = -INFINITY;
    for (int k = 0; k < nk; ++k) m = fmaxf(m, vals[(size_t)k * NPIX + p]);

    float ssum = 0.f, acc = 0.f;
    for (int rr = 0; rr < nref; ++rr) {
        int gap = cur - read_ref_index(refIdx, rr);
        bool isLong = gap > DILINT;
        float oy = 0.f, ox = 0.f;
        if (isLong) { oy = offY[rr * NPIX + p]; ox = offX[rr * NPIX + p]; }
        const float* qb = qrT + (size_t)rr * NPIX * CQ;
        for (int k = 0; k < KTOP; ++k) {
            int kk = rr * KTOP + k;
            float e = expf(vals[(size_t)kk * NPIX + p] - m);
            ssum += e;
            int id = topi[(size_t)kk * NPIX + p];
            int dr = id / PP - RAD, dc = id % PP - RAD;
            float img = 0.f;
            if (isLong) {
                float py = (float)y + oy + (float)dr;
                float px = (float)x + ox + (float)dc;
                float fy0 = floorf(py), fx0 = floorf(px);
                int y0 = (int)fy0, x0 = (int)fx0;
                float wy = py - fy0, wx = px - fx0;
                float w00 = (1.f - wy) * (1.f - wx), w01 = (1.f - wy) * wx;
                float w10 = wy * (1.f - wx), w11 = wy * wx;
                if (y0 >= 0 && y0 < HW && x0 >= 0 && x0 < HW)
                    img += w00 * qb[(y0 * HW + x0) * CQ + c];
                if (y0 >= 0 && y0 < HW && x0 + 1 >= 0 && x0 + 1 < HW)
                    img += w01 * qb[(y0 * HW + x0 + 1) * CQ + c];
                if (y0 + 1 >= 0 && y0 + 1 < HW && x0 >= 0 && x0 < HW)
                    img += w10 * qb[((y0 + 1) * HW + x0) * CQ + c];
                if (y0 + 1 >= 0 && y0 + 1 < HW && x0 + 1 >= 0 && x0 + 1 < HW)
                    img += w11 * qb[((y0 + 1) * HW + x0 + 1) * CQ + c];
            } else {
                int yy = y + dr, xx = x + dc;
                if (yy >= 0 && yy < HW && xx >= 0 && xx < HW)
                    img = qb[(yy * HW + xx) * CQ + c];
            }
            acc += e * img;
        }
    }
    out[(size_t)c * NPIX + p] = acc / ssum;
}

// ---- launcher --------------------------------------------------------------
extern "C" void kernel_launch(void* const* d_in, const int* in_sizes, int n_in,
                              void* d_out, int out_size, void* d_ws, size_t ws_size,
                              hipStream_t stream) {
    const float* fr = (const float*)d_in[0];   // (nref,1,64,48,48)
    const float* ft = (const float*)d_in[1];   // (1,64,48,48)
    const float* q  = (const float*)d_in[2];   // (nref,1,32,192,192)
    const void* refIdx = d_in[3];
    const void* curInd = d_in[4];
    int nref = in_sizes[0] / (CF * NPIX);

    float* ws  = (float*)d_ws;
    float* ftT = ws;
    float* frT = ftT + (size_t)NPIX * CF;
    float* qrT = frT + (size_t)nref * NPIX * CF;
    float* oY  = qrT + (size_t)nref * NPIX * CQ;
    float* oX  = oY + (size_t)nref * NPIX;
    float* vls = oX + (size_t)nref * NPIX;
    int* topi  = (int*)(vls + (size_t)nref * KTOP * NPIX);

    int total = NPIX * CF + nref * NPIX * CF + nref * NPIX * CQ;
    prep_kernel<<<(total + 255) / 256, 256, 0, stream>>>(fr, ft, q, nref, ftT, frT, qrT);
    corr_topk_kernel<<<dim3(NPIX, nref), 256, 0, stream>>>(ftT, frT, refIdx, curInd,
                                                           oY, oX, vls, topi);
    finalize_kernel<<<((NPIX * CQ) + 255) / 256, 256, 0, stream>>>(
        qrT, vls, topi, oY, oX, refIdx, curInd, nref, (float*)d_out);
}

// Round 2
// 258.087 us; speedup vs baseline: 1.1297x; 1.1297x over previous
//
#include <hip/hip_runtime.h>
#include <math.h>

#define HW 48
#define NPIX 2304          // 48*48
#define CF 64
#define CQ 32
#define RAD 12
#define PP 25
#define NTAP 625           // 25*25
#define KTOP 20
#define DILINT 16
#define QW 192

// ---- helpers ---------------------------------------------------------------

// ref_index may arrive as int32 or int64; detect via first 8 bytes.
__device__ inline int read_ref_index(const void* rip, int r) {
    const long long* p64 = (const long long*)rip;
    long long v0 = p64[0];
    if (v0 >= 0 && v0 < 1000000) return (int)p64[r];   // plausible int64 layout
    return ((const int*)rip)[r];                       // int32 layout
}

// 64-ch dot, A in registers. Expression kept identical to the round-1 kernel
// so correlation values (and hence top-k picks) bit-match the passing version.
__device__ inline float dotreg(const float4* __restrict__ f,
                               const float4* __restrict__ b4) {
    float s = 0.f;
#pragma unroll
    for (int i = 0; i < 16; ++i) {
        float4 aa = f[i];
        float4 bb = b4[i];
        s += aa.x * bb.x + aa.y * bb.y + aa.z * bb.z + aa.w * bb.w;
    }
    return s;
}

// ---- kernel 1: layout prep -------------------------------------------------
__global__ void prep_kernel(const float* __restrict__ fr,
                            const float* __restrict__ ft,
                            const float* __restrict__ q, int nref,
                            float* __restrict__ ftT,
                            float* __restrict__ frT,
                            float* __restrict__ qrT) {
    int i = blockIdx.x * blockDim.x + threadIdx.x;
    int tft = NPIX * CF;
    int tfr = nref * NPIX * CF;
    int tqr = nref * NPIX * CQ;
    if (i < tft) {
        int p = i >> 6, c = i & 63;
        ftT[i] = ft[c * NPIX + p];
    } else if (i < tft + tfr) {
        int j = i - tft;
        int rr = j / (NPIX * CF);
        int rem = j % (NPIX * CF);
        int p = rem >> 6, c = rem & 63;
        frT[j] = fr[((size_t)rr * CF + c) * NPIX + p];
    } else if (i < tft + tfr + tqr) {
        int j = i - tft - tfr;
        int rr = j / (NPIX * CQ);
        int rem = j % (NPIX * CQ);
        int p = rem >> 5, c = rem & 31;
        int y = p / HW, x = p % HW;
        qrT[j] = q[(((size_t)rr * CQ + c) * QW + 4 * y) * QW + 4 * x];
    }
}

// ---- kernel 2: wave-per-(pixel,ref) corr + offsets + bilinear corr + topK --
// 4 waves / 256-thread block; each wave owns one pixel. corr lives in 10
// registers per lane; all reductions are shuffle butterflies (no barriers).
__global__ __launch_bounds__(256) void corr_topk_wave(
    const float* __restrict__ ftT, const float* __restrict__ frT,
    const void* __restrict__ refIdx, const void* __restrict__ curInd,
    float* __restrict__ offY, float* __restrict__ offX,
    float* __restrict__ vals, int* __restrict__ topi) {
    __shared__ float dg[4][680];   // per-wave 26x26 corner-dot grid (long path)

    int tid = threadIdx.x;
    int wid = tid >> 6, lane = tid & 63;
    int p = blockIdx.x * 4 + wid;
    int r = blockIdx.y;
    int y = p / HW, x = p % HW;

    int cur = ((const int*)curInd)[0];
    int gap = cur - read_ref_index(refIdx, r);
    bool isLong = gap > DILINT;
    int dil = isLong ? min(4, gap / DILINT + 1) : 1;

    // ft vector (64 ch) -> 16 float4 registers, reused for every dot
    float4 f4[16];
    const float4* ftp = (const float4*)(ftT + (size_t)p * CF);
#pragma unroll
    for (int i = 0; i < 16; ++i) f4[i] = ftp[i];

    const float* frb = frT + (size_t)r * NPIX * CF;

    // 625 taps -> 10 regs/lane (tap t = lane + 64*j); invalid t -> -inf
    float creg[10];
#pragma unroll
    for (int j = 0; j < 10; ++j) {
        int t = lane + 64 * j;
        float v = -INFINITY;
        if (t < NTAP) {
            int dy = t / PP - RAD, dx = t % PP - RAD;
            int yy = y + dy * dil, xx = x + dx * dil;
            v = 0.f;
            if (yy >= 0 && yy < HW && xx >= 0 && xx < HW)
                v = dotreg(f4, (const float4*)(frb + (size_t)(yy * HW + xx) * CF));
        }
        creg[j] = v;
    }

    if (isLong) {
        // softmax over 625 taps -> expected offsets (pure shuffle reduce)
        float M = -INFINITY;
#pragma unroll
        for (int j = 0; j < 10; ++j) M = fmaxf(M, creg[j]);
#pragma unroll
        for (int s = 32; s; s >>= 1) M = fmaxf(M, __shfl_xor(M, s, 64));
        float s0 = 0.f, sy = 0.f, sx = 0.f;
#pragma unroll
        for (int j = 0; j < 10; ++j) {
            int t = lane + 64 * j;
            float e = expf(creg[j] - M);            // expf(-inf)=0 for t>=625
            int dy = t / PP - RAD, dx = t % PP - RAD;
            s0 += e; sy += e * (float)dy; sx += e * (float)dx;
        }
#pragma unroll
        for (int s = 32; s; s >>= 1) {
            s0 += __shfl_xor(s0, s, 64);
            sy += __shfl_xor(sy, s, 64);
            sx += __shfl_xor(sx, s, 64);
        }
        float oy = sy / s0 * (float)dil;
        float ox = sx / s0 * (float)dil;
        if (lane == 0) { offY[r * NPIX + p] = oy; offX[r * NPIX + p] = ox; }

        // 26x26 corner-dot grid (fractional part constant per pixel)
        float fy = (float)y + oy, fx = (float)x + ox;
        float fy0 = floorf(fy), fx0 = floorf(fx);
        float wy = fy - fy0, wx = fx - fx0;
        int iy0 = (int)fy0, ix0 = (int)fx0;
        float* dgw = dg[wid];
#pragma unroll
        for (int j = 0; j < 11; ++j) {
            int g = lane + 64 * j;
            if (g < 676) {
                int a = g / 26, bcol = g % 26;
                int yy = iy0 - RAD + a, xx = ix0 - RAD + bcol;
                float v = 0.f;
                if (yy >= 0 && yy < HW && xx >= 0 && xx < HW)
                    v = dotreg(f4, (const float4*)(frb + (size_t)(yy * HW + xx) * CF));
                dgw[g] = v;
            }
        }
        // own-wave write->read ordering only; no cross-wave dependency
        __builtin_amdgcn_wave_barrier();
        asm volatile("s_waitcnt lgkmcnt(0)" ::: "memory");
        __builtin_amdgcn_wave_barrier();

        float w00 = (1.f - wy) * (1.f - wx), w01 = (1.f - wy) * wx;
        float w10 = wy * (1.f - wx), w11 = wy * wx;
#pragma unroll
        for (int j = 0; j < 10; ++j) {
            int t = lane + 64 * j;
            if (t < NTAP) {
                int a = t / PP, bcol = t % PP;
                creg[j] = w00 * dgw[a * 26 + bcol] + w01 * dgw[a * 26 + bcol + 1] +
                          w10 * dgw[(a + 1) * 26 + bcol] + w11 * dgw[(a + 1) * 26 + bcol + 1];
            }
        }
    }

    // top-K: 20 rounds of register argmax + 6-step shuffle butterfly.
    // Tie -> lowest tap index (lax.top_k semantics).
    float* vout = vals + (size_t)r * KTOP * NPIX + p;
    int* iout = topi + (size_t)r * KTOP * NPIX + p;
    for (int k = 0; k < KTOP; ++k) {
        float bv = creg[0]; int bt = lane;
#pragma unroll
        for (int j = 1; j < 10; ++j) {
            int t = lane + 64 * j;
            if (creg[j] > bv) { bv = creg[j]; bt = t; }   // strict > keeps lowest t
        }
#pragma unroll
        for (int s = 32; s; s >>= 1) {
            float ov = __shfl_xor(bv, s, 64);
            int ot = __shfl_xor(bt, s, 64);
            if (ov > bv || (ov == bv && ot < bt)) { bv = ov; bt = ot; }
        }
        if (lane == 0) { vout[(size_t)k * NPIX] = bv; iout[(size_t)k * NPIX] = bt; }
        // clear the winner (compile-time-indexed to keep creg in registers)
        if ((bt & 63) == lane) {
            int jj = bt >> 6;
#pragma unroll
            for (int j = 0; j < 10; ++j)
                if (j == jj) creg[j] = -INFINITY;
        }
    }
}

// ---- kernel 3: softmax over 60 vals + gather colors + blend ---------------
__global__ __launch_bounds__(256) void finalize_kernel(
    const float* __restrict__ qrT, const float* __restrict__ vals,
    const int* __restrict__ topi, const float* __restrict__ offY,
    const float* __restrict__ offX, const void* __restrict__ refIdx,
    const void* __restrict__ curInd, int nref, float* __restrict__ out) {
    int tid = threadIdx.x;
    int p = blockIdx.x * 8 + (tid >> 5);
    int c = tid & 31;
    if (p >= NPIX) return;
    int y = p / HW, x = p % HW;
    int cur = ((const int*)curInd)[0];
    int nk = nref * KTOP;

    float m = -INFINITY;
    for (int k = 0; k < nk; ++k) m = fmaxf(m, vals[(size_t)k * NPIX + p]);

    float ssum = 0.f, acc = 0.f;
    for (int rr = 0; rr < nref; ++rr) {
        int gap = cur - read_ref_index(refIdx, rr);
        bool isLong = gap > DILINT;
        float oy = 0.f, ox = 0.f;
        if (isLong) { oy = offY[rr * NPIX + p]; ox = offX[rr * NPIX + p]; }
        const float* qb = qrT + (size_t)rr * NPIX * CQ;
        for (int k = 0; k < KTOP; ++k) {
            int kk = rr * KTOP + k;
            float e = expf(vals[(size_t)kk * NPIX + p] - m);
            ssum += e;
            int id = topi[(size_t)kk * NPIX + p];
            int dr = id / PP - RAD, dc = id % PP - RAD;
            float img = 0.f;
            if (isLong) {
                float py = (float)y + oy + (float)dr;
                float px = (float)x + ox + (float)dc;
                float fy0 = floorf(py), fx0 = floorf(px);
                int y0 = (int)fy0, x0 = (int)fx0;
                float wy = py - fy0, wx = px - fx0;
                float w00 = (1.f - wy) * (1.f - wx), w01 = (1.f - wy) * wx;
                float w10 = wy * (1.f - wx), w11 = wy * wx;
                if (y0 >= 0 && y0 < HW && x0 >= 0 && x0 < HW)
                    img += w00 * qb[(y0 * HW + x0) * CQ + c];
                if (y0 >= 0 && y0 < HW && x0 + 1 >= 0 && x0 + 1 < HW)
                    img += w01 * qb[(y0 * HW + x0 + 1) * CQ + c];
                if (y0 + 1 >= 0 && y0 + 1 < HW && x0 >= 0 && x0 < HW)
                    img += w10 * qb[((y0 + 1) * HW + x0) * CQ + c];
                if (y0 + 1 >= 0 && y0 + 1 < HW && x0 + 1 >= 0 && x0 + 1 < HW)
                    img += w11 * qb[((y0 + 1) * HW + x0 + 1) * CQ + c];
            } else {
                int yy = y + dr, xx = x + dc;
                if (yy >= 0 && yy < HW && xx >= 0 && xx < HW)
                    img = qb[(yy * HW + xx) * CQ + c];
            }
            acc += e * img;
        }
    }
    out[(size_t)c * NPIX + p] = acc / ssum;
}

// ---- launcher --------------------------------------------------------------
extern "C" void kernel_launch(void* const* d_in, const int* in_sizes, int n_in,
                              void* d_out, int out_size, void* d_ws, size_t ws_size,
                              hipStream_t stream) {
    const float* fr = (const float*)d_in[0];   // (nref,1,64,48,48)
    const float* ft = (const float*)d_in[1];   // (1,64,48,48)
    const float* q  = (const float*)d_in[2];   // (nref,1,32,192,192)
    const void* refIdx = d_in[3];
    const void* curInd = d_in[4];
    int nref = in_sizes[0] / (CF * NPIX);

    float* ws  = (float*)d_ws;
    float* ftT = ws;
    float* frT = ftT + (size_t)NPIX * CF;
    float* qrT = frT + (size_t)nref * NPIX * CF;
    float* oY  = qrT + (size_t)nref * NPIX * CQ;
    float* oX  = oY + (size_t)nref * NPIX;
    float* vls = oX + (size_t)nref * NPIX;
    int* topi  = (int*)(vls + (size_t)nref * KTOP * NPIX);

    int total = NPIX * CF + nref * NPIX * CF + nref * NPIX * CQ;
    prep_kernel<<<(total + 255) / 256, 256, 0, stream>>>(fr, ft, q, nref, ftT, frT, qrT);
    corr_topk_wave<<<dim3(NPIX / 4, nref), 256, 0, stream>>>(ftT, frT, refIdx, curInd,
                                                             oY, oX, vls, topi);
    finalize_kernel<<<((NPIX * CQ) + 255) / 256, 256, 0, stream>>>(
        qrT, vls, topi, oY, oX, refIdx, curInd, nref, (float*)d_out);
}

// Round 3
// 210.793 us; speedup vs baseline: 1.3832x; 1.2244x over previous
//
#include <hip/hip_runtime.h>
#include <math.h>

#define HW 48
#define NPIX 2304          // 48*48
#define CF 64
#define CQ 32
#define RAD 12
#define PP 25
#define NTAP 625           // 25*25
#define KTOP 20
#define DILINT 16
#define QW 192

// ---- helpers ---------------------------------------------------------------

// ref_index may arrive as int32 or int64; detect via first 8 bytes.
__device__ inline int read_ref_index(const void* rip, int r) {
    const long long* p64 = (const long long*)rip;
    long long v0 = p64[0];
    if (v0 >= 0 && v0 < 1000000) return (int)p64[r];   // plausible int64 layout
    return ((const int*)rip)[r];                       // int32 layout
}

// ---- kernel 1: layout prep -------------------------------------------------
__global__ void prep_kernel(const float* __restrict__ fr,
                            const float* __restrict__ ft,
                            const float* __restrict__ q, int nref,
                            float* __restrict__ ftT,
                            float* __restrict__ frT,
                            float* __restrict__ qrT) {
    int i = blockIdx.x * blockDim.x + threadIdx.x;
    int tft = NPIX * CF;
    int tfr = nref * NPIX * CF;
    int tqr = nref * NPIX * CQ;
    if (i < tft) {
        int p = i >> 6, c = i & 63;
        ftT[i] = ft[c * NPIX + p];
    } else if (i < tft + tfr) {
        int j = i - tft;
        int rr = j / (NPIX * CF);
        int rem = j % (NPIX * CF);
        int p = rem >> 6, c = rem & 63;
        frT[j] = fr[((size_t)rr * CF + c) * NPIX + p];
    } else if (i < tft + tfr + tqr) {
        int j = i - tft - tfr;
        int rr = j / (NPIX * CQ);
        int rem = j % (NPIX * CQ);
        int p = rem >> 5, c = rem & 31;
        int y = p / HW, x = p % HW;
        qrT[j] = q[(((size_t)rr * CQ + c) * QW + 4 * y) * QW + 4 * x];
    }
}

// ---- kernel 2: wave-per-(pixel,ref), cooperative 16-lane dots --------------
// Each 16-lane group computes one tap dot (lane holds 4 channels); the 4
// groups of a wave take 4 consecutive tap indices -> ~1KB contiguous reads.
// Tap values stored in per-wave LDS (stride-64 reads = free 2-way aliasing).
__global__ __launch_bounds__(256) void corr_topk_wave(
    const float* __restrict__ ftT, const float* __restrict__ frT,
    const void* __restrict__ refIdx, const void* __restrict__ curInd,
    float* __restrict__ offY, float* __restrict__ offX,
    float* __restrict__ vals, int* __restrict__ topi) {
    __shared__ float corrLds[4][640];
    __shared__ float dg[4][680];

    int tid = threadIdx.x;
    int wid = tid >> 6, lane = tid & 63;
    int g = lane >> 4;          // tap slot within round (0..3)
    int cs = lane & 15;         // channel slice (4 floats each)
    int p = blockIdx.x * 4 + wid;
    int r = blockIdx.y;
    int y = p / HW, x = p % HW;

    int cur = ((const int*)curInd)[0];
    int gap = cur - read_ref_index(refIdx, r);
    bool isLong = gap > DILINT;
    int dil = isLong ? min(4, gap / DILINT + 1) : 1;

    // this lane's 4-channel slice of ft[p]
    float4 fq = ((const float4*)(ftT + (size_t)p * CF))[cs];
    const float* frb = frT + (size_t)r * NPIX * CF;
    float* cw = corrLds[wid];

    // ---- integer-tap pass: 157 rounds x 4 taps -----------------------------
    for (int rr = 0; rr < 157; ++rr) {
        int t = 4 * rr + g;
        float s = 0.f;
        bool valid = t < NTAP;
        if (valid) {
            int dy = t / PP - RAD, dx = t % PP - RAD;
            int yy = y + dy * dil, xx = x + dx * dil;
            if (yy >= 0 && yy < HW && xx >= 0 && xx < HW) {
                float4 b = ((const float4*)(frb + (size_t)(yy * HW + xx) * CF))[cs];
                s = fq.x * b.x + fq.y * b.y + fq.z * b.z + fq.w * b.w;
            }
        }
        s += __shfl_xor(s, 1, 64);
        s += __shfl_xor(s, 2, 64);
        s += __shfl_xor(s, 4, 64);
        s += __shfl_xor(s, 8, 64);
        if (cs == 0 && valid) cw[t] = s;
    }
    // own-wave LDS write->read ordering (no cross-wave deps)
    __builtin_amdgcn_wave_barrier();
    asm volatile("s_waitcnt lgkmcnt(0)" ::: "memory");
    __builtin_amdgcn_sched_barrier(0);

    if (isLong) {
        // softmax over 625 taps -> expected offsets (shuffle reduce)
        float M = -INFINITY;
#pragma unroll
        for (int j = 0; j < 10; ++j) {
            int t = lane + 64 * j;
            float v = (t < NTAP) ? cw[t] : -INFINITY;
            M = fmaxf(M, v);
        }
#pragma unroll
        for (int s = 32; s; s >>= 1) M = fmaxf(M, __shfl_xor(M, s, 64));
        float s0 = 0.f, sy = 0.f, sx = 0.f;
#pragma unroll
        for (int j = 0; j < 10; ++j) {
            int t = lane + 64 * j;
            if (t < NTAP) {
                float e = expf(cw[t] - M);
                int dy = t / PP - RAD, dx = t % PP - RAD;
                s0 += e; sy += e * (float)dy; sx += e * (float)dx;
            }
        }
#pragma unroll
        for (int s = 32; s; s >>= 1) {
            s0 += __shfl_xor(s0, s, 64);
            sy += __shfl_xor(sy, s, 64);
            sx += __shfl_xor(sx, s, 64);
        }
        float oy = sy / s0 * (float)dil;
        float ox = sx / s0 * (float)dil;
        if (lane == 0) { offY[r * NPIX + p] = oy; offX[r * NPIX + p] = ox; }

        // 26x26 corner-dot grid, cooperative dots (169 rounds x 4)
        float fy = (float)y + oy, fx = (float)x + ox;
        float fy0 = floorf(fy), fx0 = floorf(fx);
        float wy = fy - fy0, wx = fx - fx0;
        int iy0 = (int)fy0, ix0 = (int)fx0;
        float* dgw = dg[wid];
        for (int rr = 0; rr < 169; ++rr) {
            int idx = 4 * rr + g;
            int a = idx / 26, bcol = idx % 26;
            int yy = iy0 - RAD + a, xx = ix0 - RAD + bcol;
            float s = 0.f;
            if (yy >= 0 && yy < HW && xx >= 0 && xx < HW) {
                float4 b = ((const float4*)(frb + (size_t)(yy * HW + xx) * CF))[cs];
                s = fq.x * b.x + fq.y * b.y + fq.z * b.z + fq.w * b.w;
            }
            s += __shfl_xor(s, 1, 64);
            s += __shfl_xor(s, 2, 64);
            s += __shfl_xor(s, 4, 64);
            s += __shfl_xor(s, 8, 64);
            if (cs == 0) dgw[idx] = s;
        }
        __builtin_amdgcn_wave_barrier();
        asm volatile("s_waitcnt lgkmcnt(0)" ::: "memory");
        __builtin_amdgcn_sched_barrier(0);

        float w00 = (1.f - wy) * (1.f - wx), w01 = (1.f - wy) * wx;
        float w10 = wy * (1.f - wx), w11 = wy * wx;
#pragma unroll
        for (int j = 0; j < 10; ++j) {
            int t = lane + 64 * j;
            if (t < NTAP) {
                int a = t / PP, bcol = t % PP;
                cw[t] = w00 * dgw[a * 26 + bcol] + w01 * dgw[a * 26 + bcol + 1] +
                        w10 * dgw[(a + 1) * 26 + bcol] + w11 * dgw[(a + 1) * 26 + bcol + 1];
            }
        }
        __builtin_amdgcn_wave_barrier();
        asm volatile("s_waitcnt lgkmcnt(0)" ::: "memory");
        __builtin_amdgcn_sched_barrier(0);
    }

    // pull taps into registers, then top-K exactly as round 2
    float creg[10];
#pragma unroll
    for (int j = 0; j < 10; ++j) {
        int t = lane + 64 * j;
        creg[j] = (t < NTAP) ? cw[t] : -INFINITY;
    }

    float* vout = vals + (size_t)r * KTOP * NPIX + p;
    int* iout = topi + (size_t)r * KTOP * NPIX + p;
    for (int k = 0; k < KTOP; ++k) {
        float bv = creg[0]; int bt = lane;
#pragma unroll
        for (int j = 1; j < 10; ++j) {
            int t = lane + 64 * j;
            if (creg[j] > bv) { bv = creg[j]; bt = t; }   // strict > keeps lowest t
        }
#pragma unroll
        for (int s = 32; s; s >>= 1) {
            float ov = __shfl_xor(bv, s, 64);
            int ot = __shfl_xor(bt, s, 64);
            if (ov > bv || (ov == bv && ot < bt)) { bv = ov; bt = ot; }
        }
        if (lane == 0) { vout[(size_t)k * NPIX] = bv; iout[(size_t)k * NPIX] = bt; }
        if ((bt & 63) == lane) {
            int jj = bt >> 6;
#pragma unroll
            for (int j = 0; j < 10; ++j)
                if (j == jj) creg[j] = -INFINITY;
        }
    }
}

// ---- kernel 3: softmax over 60 vals + gather colors + blend ---------------
__global__ __launch_bounds__(256) void finalize_kernel(
    const float* __restrict__ qrT, const float* __restrict__ vals,
    const int* __restrict__ topi, const float* __restrict__ offY,
    const float* __restrict__ offX, const void* __restrict__ refIdx,
    const void* __restrict__ curInd, int nref, float* __restrict__ out) {
    int tid = threadIdx.x;
    int p = blockIdx.x * 8 + (tid >> 5);
    int c = tid & 31;
    if (p >= NPIX) return;
    int y = p / HW, x = p % HW;
    int cur = ((const int*)curInd)[0];
    int nk = nref * KTOP;

    float m = -INFINITY;
    for (int k = 0; k < nk; ++k) m = fmaxf(m, vals[(size_t)k * NPIX + p]);

    float ssum = 0.f, acc = 0.f;
    for (int rr = 0; rr < nref; ++rr) {
        int gap = cur - read_ref_index(refIdx, rr);
        bool isLong = gap > DILINT;
        float oy = 0.f, ox = 0.f;
        if (isLong) { oy = offY[rr * NPIX + p]; ox = offX[rr * NPIX + p]; }
        const float* qb = qrT + (size_t)rr * NPIX * CQ;
        for (int k = 0; k < KTOP; ++k) {
            int kk = rr * KTOP + k;
            float e = expf(vals[(size_t)kk * NPIX + p] - m);
            ssum += e;
            int id = topi[(size_t)kk * NPIX + p];
            int dr = id / PP - RAD, dc = id % PP - RAD;
            float img = 0.f;
            if (isLong) {
                float py = (float)y + oy + (float)dr;
                float px = (float)x + ox + (float)dc;
                float fy0 = floorf(py), fx0 = floorf(px);
                int y0 = (int)fy0, x0 = (int)fx0;
                float wy = py - fy0, wx = px - fx0;
                float w00 = (1.f - wy) * (1.f - wx), w01 = (1.f - wy) * wx;
                float w10 = wy * (1.f - wx), w11 = wy * wx;
                if (y0 >= 0 && y0 < HW && x0 >= 0 && x0 < HW)
                    img += w00 * qb[(y0 * HW + x0) * CQ + c];
                if (y0 >= 0 && y0 < HW && x0 + 1 >= 0 && x0 + 1 < HW)
                    img += w01 * qb[(y0 * HW + x0 + 1) * CQ + c];
                if (y0 + 1 >= 0 && y0 + 1 < HW && x0 >= 0 && x0 < HW)
                    img += w10 * qb[((y0 + 1) * HW + x0) * CQ + c];
                if (y0 + 1 >= 0 && y0 + 1 < HW && x0 + 1 >= 0 && x0 + 1 < HW)
                    img += w11 * qb[((y0 + 1) * HW + x0 + 1) * CQ + c];
            } else {
                int yy = y + dr, xx = x + dc;
                if (yy >= 0 && yy < HW && xx >= 0 && xx < HW)
                    img = qb[(yy * HW + xx) * CQ + c];
            }
            acc += e * img;
        }
    }
    out[(size_t)c * NPIX + p] = acc / ssum;
}

// ---- launcher --------------------------------------------------------------
extern "C" void kernel_launch(void* const* d_in, const int* in_sizes, int n_in,
                              void* d_out, int out_size, void* d_ws, size_t ws_size,
                              hipStream_t stream) {
    const float* fr = (const float*)d_in[0];   // (nref,1,64,48,48)
    const float* ft = (const float*)d_in[1];   // (1,64,48,48)
    const float* q  = (const float*)d_in[2];   // (nref,1,32,192,192)
    const void* refIdx = d_in[3];
    const void* curInd = d_in[4];
    int nref = in_sizes[0] / (CF * NPIX);

    float* ws  = (float*)d_ws;
    float* ftT = ws;
    float* frT = ftT + (size_t)NPIX * CF;
    float* qrT = frT + (size_t)nref * NPIX * CF;
    float* oY  = qrT + (size_t)nref * NPIX * CQ;
    float* oX  = oY + (size_t)nref * NPIX;
    float* vls = oX + (size_t)nref * NPIX;
    int* topi  = (int*)(vls + (size_t)nref * KTOP * NPIX);

    int total = NPIX * CF + nref * NPIX * CF + nref * NPIX * CQ;
    prep_kernel<<<(total + 255) / 256, 256, 0, stream>>>(fr, ft, q, nref, ftT, frT, qrT);
    corr_topk_wave<<<dim3(NPIX / 4, nref), 256, 0, stream>>>(ftT, frT, refIdx, curInd,
                                                             oY, oX, vls, topi);
    finalize_kernel<<<((NPIX * CQ) + 255) / 256, 256, 0, stream>>>(
        qrT, vls, topi, oY, oX, refIdx, curInd, nref, (float*)d_out);
}